// Round 11
// baseline (1052.713 us; speedup 1.0000x reference)
//
#include <hip/hip_runtime.h>
#include <cstdint>
#include <math.h>

#define B_  64
#define L_  256
#define V_  256
#define E_  256
#define H_  1024
#define H3  3072

typedef __bf16 bf16x8 __attribute__((ext_vector_type(8)));
typedef float  f32x4  __attribute__((ext_vector_type(4)));

__device__ __forceinline__ unsigned short f2bf(float f) {
    union { float f; unsigned u; } v; v.f = f;
    unsigned r = v.u + 0x7fffu + ((v.u >> 16) & 1u);   // round-to-nearest-even
    return (unsigned short)(r >> 16);
}

// ---- prep: tiled fp32 [rows][cols] -> bf16 [cols][rows] ----
__global__ __launch_bounds__(256) void prep_transpose_tiled(const float* __restrict__ src,
                                                            unsigned short* __restrict__ dst,
                                                            int rows, int cols) {
    __shared__ unsigned short tile[32][34];
    int n0 = blockIdx.x * 32;
    int k0 = blockIdx.y * 32;
    int tx = threadIdx.x & 31, ty = threadIdx.x >> 5;
#pragma unroll
    for (int j = 0; j < 32; j += 8) {
        float v = src[(size_t)(k0 + ty + j) * cols + (n0 + tx)];
        tile[tx][ty + j] = f2bf(v);
    }
    __syncthreads();
#pragma unroll
    for (int j = 0; j < 32; j += 8)
        dst[(size_t)(n0 + ty + j) * rows + (k0 + tx)] = tile[ty + j][tx];
}

// ---- prep: embedding fp32->bf16, zero h0 (bf16), zero flags ----
__global__ void prep_misc(const float* __restrict__ emb,
                          unsigned short* __restrict__ embB,
                          unsigned short* __restrict__ h0b,
                          unsigned* __restrict__ flags) {
    int idx = blockIdx.x * 256 + threadIdx.x;   // 65536 = V*E = B*H
    embB[idx] = f2bf(emb[idx]);
    h0b[idx]  = 0;
    if (idx < 4096) flags[idx] = 0;
}

// ---- phase 2: persistent GRU; R6 flag protocol + R7 fused xw ----
// grid = 256 blocks (btile = bid&3 over 16 batches, jtile = bid>>2 over 16 h-cols).
// flag(btile,j) at flagp[(btile*64+j)*16] (64 B apart), monotone = steps done.
__global__ __launch_bounds__(256, 1) void gru_persistent(
        unsigned short* __restrict__ hbuf0,
        unsigned short* __restrict__ hbuf1,
        const unsigned short* __restrict__ WhT,   // [3H][H]
        const unsigned short* __restrict__ WiT,   // [3H][E]
        const unsigned short* __restrict__ embB,  // [V][E]
        const int* __restrict__ tokens,           // [B][L]
        const float* __restrict__ bh,
        unsigned short* __restrict__ yB,          // [B][L][H]
        unsigned* __restrict__ flagp) {
    __shared__ f32x4 red[2][4][6][64];            // [parity][wave][slot][lane]

    int bid = blockIdx.x;
    int btile = bid & 3;             // 4 tiles of 16 batches (independent groups)
    int jtile = bid >> 2;            // 64 tiles of 16 h-cols
    int wave = threadIdx.x >> 6, lane = threadIdx.x & 63;
    int l16 = lane & 15, q = lane >> 4;
    int b0 = btile * 16, j0 = jtile * 16;
    int kbase = wave * 256;          // K split across the 4 waves

    unsigned* grpflags = flagp + (btile << 10);       // 64 flags, stride 16 words
    unsigned* myflag   = grpflags + (jtile << 4);

    // ---- pin Wh fragments (96 VGPR/lane) ----
    bf16x8 Wreg[3][8];
#pragma unroll
    for (int g = 0; g < 3; g++) {
        const bf16x8* Brow = (const bf16x8*)(WhT + (size_t)(g * H_ + j0 + l16) * H_);
#pragma unroll
        for (int kk = 0; kk < 8; kk++) {
            Wreg[g][kk] = Brow[(kbase >> 3) + kk * 4 + q];
            asm volatile("" : "+v"(Wreg[g][kk]));   // opaque: forbid rematerialization
        }
    }
    // ---- pin Wi fragments (24 VGPR/lane): K=256 split 4 waves x 64 ----
    bf16x8 Wxreg[3][2];
#pragma unroll
    for (int g = 0; g < 3; g++) {
        const bf16x8* Bx = (const bf16x8*)(WiT + (size_t)(g * H_ + j0 + l16) * E_);
#pragma unroll
        for (int c = 0; c < 2; c++) {
            Wxreg[g][c] = Bx[wave * 8 + c * 4 + q];
            asm volatile("" : "+v"(Wxreg[g][c]));
        }
    }

    // ---- per-thread gate mapping / biases / fp32 state ----
    int Lp  = threadIdx.x & 63;
    int reg = threadIdx.x >> 6;
    int b_local = (Lp >> 4) * 4 + reg;   // C row
    int j_local = Lp & 15;               // C col
    int b = b0 + b_local, jg = j0 + j_local;
    float bhr = bh[jg];
    float bhz = bh[H_ + jg];
    float bhn = bh[2 * H_ + jg];
    asm volatile("" : "+v"(bhr), "+v"(bhz), "+v"(bhn));
    float hreg = 0.0f;                   // fp32 hidden state for (b, jg)

    const int tokrow = (b0 + l16) * L_;  // token row for this lane's A-row

    unsigned short* hcur = hbuf0;        // zeroed by prep_misc
    unsigned short* hnxt = hbuf1;

    for (int t = 0; t < L_; t++) {
        int par = t & 1;

        // ---- xw partials for this step (h-independent; before the wait) ----
        int tok = tokens[tokrow + t];
        const bf16x8* Ax = (const bf16x8*)(embB + (size_t)tok * E_);
        bf16x8 ax0 = Ax[wave * 8 + q];
        bf16x8 ax1 = Ax[wave * 8 + 4 + q];
        f32x4 xacc[3] = {};
#pragma unroll
        for (int g = 0; g < 3; g++) {
            xacc[g] = __builtin_amdgcn_mfma_f32_16x16x32_bf16(ax0, Wxreg[g][0], xacc[g], 0, 0, 0);
            xacc[g] = __builtin_amdgcn_mfma_f32_16x16x32_bf16(ax1, Wxreg[g][1], xacc[g], 0, 0, 0);
        }

        // ---- wait for all 64 group blocks to have completed step t-1 ----
        if (t > 0) {
            if (wave == 0) {
                unsigned tgt = (unsigned)t;
                int spins = 0;
                while (true) {
                    unsigned f = __hip_atomic_load(grpflags + (lane << 4),
                                                   __ATOMIC_RELAXED,
                                                   __HIP_MEMORY_SCOPE_AGENT);
                    if (__all((int)(f >= tgt))) break;
                    if (++spins > (1 << 20)) break;   // fail loud, never hang
                    __builtin_amdgcn_s_sleep(1);
                }
            }
            __syncthreads();   // release waves 1-3
        }

        // ---- coherent (IC) loads of h A-fragments ----
        const unsigned short* p = hcur + (size_t)(b0 + l16) * H_ + kbase + q * 8;
        bf16x8 a0, a1, a2, a3, a4, a5, a6, a7;
        asm volatile("global_load_dwordx4 %0, %1, off sc0 sc1" : "=v"(a0) : "v"(p));
        asm volatile("global_load_dwordx4 %0, %1, off sc0 sc1" : "=v"(a1) : "v"(p + 32));
        asm volatile("global_load_dwordx4 %0, %1, off sc0 sc1" : "=v"(a2) : "v"(p + 64));
        asm volatile("global_load_dwordx4 %0, %1, off sc0 sc1" : "=v"(a3) : "v"(p + 96));
        asm volatile("global_load_dwordx4 %0, %1, off sc0 sc1" : "=v"(a4) : "v"(p + 128));
        asm volatile("global_load_dwordx4 %0, %1, off sc0 sc1" : "=v"(a5) : "v"(p + 160));
        asm volatile("global_load_dwordx4 %0, %1, off sc0 sc1" : "=v"(a6) : "v"(p + 192));
        asm volatile("global_load_dwordx4 %0, %1, off sc0 sc1" : "=v"(a7) : "v"(p + 224));
        asm volatile("s_waitcnt vmcnt(0)"
                     : "+v"(a0), "+v"(a1), "+v"(a2), "+v"(a3),
                       "+v"(a4), "+v"(a5), "+v"(a6), "+v"(a7)
                     :: "memory");

        // ---- h @ Wh ----
        f32x4 acc[3] = {};
#pragma unroll
        for (int g = 0; g < 3; g++) {
            acc[g] = __builtin_amdgcn_mfma_f32_16x16x32_bf16(a0, Wreg[g][0], acc[g], 0, 0, 0);
            acc[g] = __builtin_amdgcn_mfma_f32_16x16x32_bf16(a1, Wreg[g][1], acc[g], 0, 0, 0);
            acc[g] = __builtin_amdgcn_mfma_f32_16x16x32_bf16(a2, Wreg[g][2], acc[g], 0, 0, 0);
            acc[g] = __builtin_amdgcn_mfma_f32_16x16x32_bf16(a3, Wreg[g][3], acc[g], 0, 0, 0);
            acc[g] = __builtin_amdgcn_mfma_f32_16x16x32_bf16(a4, Wreg[g][4], acc[g], 0, 0, 0);
            acc[g] = __builtin_amdgcn_mfma_f32_16x16x32_bf16(a5, Wreg[g][5], acc[g], 0, 0, 0);
            acc[g] = __builtin_amdgcn_mfma_f32_16x16x32_bf16(a6, Wreg[g][6], acc[g], 0, 0, 0);
            acc[g] = __builtin_amdgcn_mfma_f32_16x16x32_bf16(a7, Wreg[g][7], acc[g], 0, 0, 0);
        }
#pragma unroll
        for (int g = 0; g < 3; g++) {
            red[par][wave][g][lane]     = acc[g];
            red[par][wave][3 + g][lane] = xacc[g];
        }
        __syncthreads();   // (A) red ready

        float gh0 = red[par][0][0][Lp][reg] + red[par][1][0][Lp][reg] + red[par][2][0][Lp][reg] + red[par][3][0][Lp][reg];
        float gh1 = red[par][0][1][Lp][reg] + red[par][1][1][Lp][reg] + red[par][2][1][Lp][reg] + red[par][3][1][Lp][reg];
        float gh2 = red[par][0][2][Lp][reg] + red[par][1][2][Lp][reg] + red[par][2][2][Lp][reg] + red[par][3][2][Lp][reg];
        float xr  = red[par][0][3][Lp][reg] + red[par][1][3][Lp][reg] + red[par][2][3][Lp][reg] + red[par][3][3][Lp][reg];
        float xz  = red[par][0][4][Lp][reg] + red[par][1][4][Lp][reg] + red[par][2][4][Lp][reg] + red[par][3][4][Lp][reg];
        float xn  = red[par][0][5][Lp][reg] + red[par][1][5][Lp][reg] + red[par][2][5][Lp][reg] + red[par][3][5][Lp][reg];

        float r = 1.0f / (1.0f + __expf(-(xr + gh0 + bhr)));
        float z = 1.0f / (1.0f + __expf(-(xz + gh1 + bhz)));
        float n = tanhf(xn + r * (gh2 + bhn));
        float hnew = (1.0f - z) * n + z * hreg;
        hreg = hnew;

        unsigned short hbv = f2bf(hnew);
        // coherent write-through h store (visible at IC once vmcnt retires)
        {
            unsigned short* hp = hnxt + (size_t)b * H_ + jg;
            unsigned hv32 = hbv;
            asm volatile("global_store_short %0, %1, off sc0 sc1"
                         :: "v"(hp), "v"(hv32) : "memory");
        }
        asm volatile("s_waitcnt vmcnt(0)" ::: "memory");
        __syncthreads();   // (B) all h stores of this block are at IC

        if (threadIdx.x == 0)
            __hip_atomic_store(myflag, (unsigned)(t + 1), __ATOMIC_RELAXED,
                               __HIP_MEMORY_SCOPE_AGENT);

        yB[((size_t)b * L_ + t) * H_ + jg] = hbv;   // cached; off critical path

        unsigned short* tmp = hcur; hcur = hnxt; hnxt = tmp;
    }
}

// ---- phase 3: logits[m][v] = y[m] @ Wout + bout   (M=16384, K=1024, N=256) ----
__global__ __launch_bounds__(256) void out_gemm(const unsigned short* __restrict__ yB,
                                                const unsigned short* __restrict__ WoutT,
                                                const float* __restrict__ bout,
                                                float* __restrict__ out) {
    int ntile = blockIdx.x;          // 4 tiles of 64 cols
    int mtile = blockIdx.y;          // 256 tiles of 64 rows
    int wave = threadIdx.x >> 6, lane = threadIdx.x & 63;
    int l16 = lane & 15, q = lane >> 4;

    int m = mtile * 64 + wave * 16 + l16;
    const bf16x8* Arow = (const bf16x8*)(yB + (size_t)m * H_);
    int n0 = ntile * 64;

    f32x4 acc[4] = {};
    for (int k0 = 0; k0 < H_; k0 += 32) {
        bf16x8 a = Arow[(k0 >> 3) + q];
#pragma unroll
        for (int j = 0; j < 4; j++) {
            const bf16x8* Brow = (const bf16x8*)(WoutT + (size_t)(n0 + j*16 + l16) * H_);
            bf16x8 b = Brow[(k0 >> 3) + q];
            acc[j] = __builtin_amdgcn_mfma_f32_16x16x32_bf16(a, b, acc[j], 0, 0, 0);
        }
    }
    int mrow = mtile * 64 + wave * 16 + q * 4;
#pragma unroll
    for (int j = 0; j < 4; j++) {
        int n = n0 + j * 16 + l16;
        float bias = bout[n];
#pragma unroll
        for (int r = 0; r < 4; r++)
            out[(size_t)(mrow + r) * V_ + n] = acc[j][r] + bias;
    }
}

extern "C" void kernel_launch(void* const* d_in, const int* in_sizes, int n_in,
                              void* d_out, int out_size, void* d_ws, size_t ws_size,
                              hipStream_t stream) {
    const int*   tokens = (const int*)  d_in[0];
    const float* emb    = (const float*)d_in[1];
    const float* Wi     = (const float*)d_in[2];
    const float* Wh     = (const float*)d_in[3];
    const float* bh     = (const float*)d_in[4];
    const float* Wout   = (const float*)d_in[5];
    const float* bout   = (const float*)d_in[6];
    float* out = (float*)d_out;

    char* ws = (char*)d_ws;
    size_t off = 0;
    auto alloc = [&](size_t bytes) -> void* {
        void* p = ws + off;
        off += (bytes + 255) & ~(size_t)255;
        return p;
    };
    unsigned short* WhT   = (unsigned short*)alloc((size_t)H3 * H_ * 2);   // 6 MB
    unsigned short* WiT   = (unsigned short*)alloc((size_t)H3 * E_ * 2);   // 1.5 MB
    unsigned short* WoutT = (unsigned short*)alloc((size_t)V_ * H_ * 2);   // 0.5 MB
    unsigned short* embB  = (unsigned short*)alloc((size_t)V_ * E_ * 2);   // 128 KB
    unsigned short* yB    = (unsigned short*)alloc((size_t)B_ * L_ * H_ * 2); // 32 MB
    unsigned short* hb0   = (unsigned short*)alloc((size_t)B_ * H_ * 2);   // 128 KB
    unsigned short* hb1   = (unsigned short*)alloc((size_t)B_ * H_ * 2);   // 128 KB
    unsigned*       flags = (unsigned*)alloc(4096 * sizeof(unsigned));

    prep_transpose_tiled<<<dim3(H3 / 32, H_ / 32), 256, 0, stream>>>(Wh, WhT, H_, H3);
    prep_transpose_tiled<<<dim3(H3 / 32, E_ / 32), 256, 0, stream>>>(Wi, WiT, E_, H3);
    prep_transpose_tiled<<<dim3(V_ / 32, H_ / 32), 256, 0, stream>>>(Wout, WoutT, H_, V_);
    prep_misc<<<(V_ * E_) / 256, 256, 0, stream>>>(emb, embB, hb0, flags);

    {
        unsigned short* a0 = hb0; unsigned short* a1 = hb1;
        const unsigned short* aW = WhT; const unsigned short* aWx = WiT;
        const unsigned short* ae = embB; const int* at = tokens;
        const float* ab = bh; unsigned short* ay = yB;
        unsigned* af = flags;
        void* args[] = {&a0, &a1, &aW, &aWx, &ae, &at, &ab, &ay, &af};
        hipError_t err = hipLaunchCooperativeKernel((void*)gru_persistent,
                                                    dim3(256), dim3(256), args, 0, stream);
        if (err != hipSuccess) {
            // fallback: plain launch; 256 blocks at 1 block/CU co-reside on 256 CUs,
            // and all spins are bounded (fail loud via absmax, not hang)
            gru_persistent<<<dim3(256), dim3(256), 0, stream>>>(
                a0, a1, aW, aWx, ae, at, ab, ay, af);
        }
    }

    out_gemm<<<dim3(4, 256), 256, 0, stream>>>(yB, WoutT, bout, out);
}

// Round 12
// 973.121 us; speedup vs baseline: 1.0818x; 1.0818x over previous
//
#include <hip/hip_runtime.h>
#include <cstdint>
#include <math.h>

#define B_  64
#define L_  256
#define V_  256
#define E_  256
#define H_  1024
#define H3  3072

typedef __bf16 bf16x8 __attribute__((ext_vector_type(8)));
typedef float  f32x4  __attribute__((ext_vector_type(4)));

__device__ __forceinline__ unsigned short f2bf(float f) {
    union { float f; unsigned u; } v; v.f = f;
    unsigned r = v.u + 0x7fffu + ((v.u >> 16) & 1u);   // round-to-nearest-even
    return (unsigned short)(r >> 16);
}

// ok iff NO 16-bit half of any dword equals the 0xAAAA poison sentinel
__device__ __forceinline__ int chunk_ok(bf16x8 v) {
    union { bf16x8 b; unsigned u[4]; } cv; cv.b = v;
    int ok = 1;
#pragma unroll
    for (int i = 0; i < 4; i++) {
        unsigned x = cv.u[i] ^ 0xAAAAAAAAu;
        ok &= (int)((x & 0xFFFFu) != 0u) & (int)((x >> 16) != 0u);
    }
    return ok;
}

// ---- single prep kernel: 3 transposes + emb convert + h0 zero + hist poison ----
// grid regions: [0,3072) WhT tiles; [3072,3840) WiT; [3840,4096) WoutT;
// [4096,4352) embB+h0; [4352,12544) poison slots 1..256.
__global__ __launch_bounds__(256) void prep_all(
        const float* __restrict__ Wh, const float* __restrict__ Wi,
        const float* __restrict__ Wout, const float* __restrict__ emb,
        unsigned short* __restrict__ WhT, unsigned short* __restrict__ WiT,
        unsigned short* __restrict__ WoutT, unsigned short* __restrict__ embB,
        unsigned short* __restrict__ h0b, uint4* __restrict__ poison) {
    __shared__ unsigned short tile[32][34];
    int bid = blockIdx.x;
    const float* src; unsigned short* dst; int rows, cols, nt, kt;
    if (bid < 3072)      { src = Wh;   dst = WhT;   rows = H_; cols = H3; nt = bid % 96; kt = bid / 96; }
    else if (bid < 3840) { int b = bid - 3072; src = Wi;   dst = WiT;   rows = E_; cols = H3; nt = b % 96; kt = b / 96; }
    else if (bid < 4096) { int b = bid - 3840; src = Wout; dst = WoutT; rows = H_; cols = V_; nt = b % 8;  kt = b / 8; }
    else if (bid < 4352) {
        int idx = (bid - 4096) * 256 + threadIdx.x;   // 65536 = V*E = B*H
        embB[idx] = f2bf(emb[idx]);
        h0b[idx]  = 0;
        return;
    } else {
        size_t T = (size_t)(bid - 4352) * 256 + threadIdx.x;   // 2M uint4 = 33.55 MB
        uint4 v; v.x = v.y = v.z = v.w = 0xAAAAAAAAu;
        poison[T] = v;
        return;
    }
    int n0 = nt * 32, k0 = kt * 32;
    int tx = threadIdx.x & 31, ty = threadIdx.x >> 5;
#pragma unroll
    for (int j = 0; j < 32; j += 8)
        tile[tx][ty + j] = f2bf(src[(size_t)(k0 + ty + j) * cols + (n0 + tx)]);
    __syncthreads();
#pragma unroll
    for (int j = 0; j < 32; j += 8)
        dst[(size_t)(n0 + ty + j) * rows + (k0 + tx)] = tile[ty + j][tx];
}

// ---- phase 2: persistent GRU; flagless write-once dataflow, fused xw,
//      chunked poll with MFMA overlap ----
__global__ __launch_bounds__(256, 1) void gru_persistent(
        unsigned short* __restrict__ hist,        // [257][B][H], slot0=0, rest poisoned
        const unsigned short* __restrict__ WhT,   // [3H][H]
        const unsigned short* __restrict__ WiT,   // [3H][E]
        const unsigned short* __restrict__ embB,  // [V][E]
        const int* __restrict__ tokens,           // [B][L]
        const float* __restrict__ bh,
        unsigned short* __restrict__ yB) {        // [B][L][H]
    __shared__ f32x4 red[2][4][6][64];            // [parity][wave][slot][lane]

    int bid = blockIdx.x;
    int btile = bid & 3;
    int jtile = bid >> 2;
    int wave = threadIdx.x >> 6, lane = threadIdx.x & 63;
    int l16 = lane & 15, q = lane >> 4;
    int b0 = btile * 16, j0 = jtile * 16;
    int kbase = wave * 256;

    // ---- pin Wh fragments (96 VGPR/lane) ----
    bf16x8 Wreg[3][8];
#pragma unroll
    for (int g = 0; g < 3; g++) {
        const bf16x8* Brow = (const bf16x8*)(WhT + (size_t)(g * H_ + j0 + l16) * H_);
#pragma unroll
        for (int kk = 0; kk < 8; kk++) {
            Wreg[g][kk] = Brow[(kbase >> 3) + kk * 4 + q];
            asm volatile("" : "+v"(Wreg[g][kk]));
        }
    }
    // ---- pin Wi fragments (24 VGPR/lane) ----
    bf16x8 Wxreg[3][2];
#pragma unroll
    for (int g = 0; g < 3; g++) {
        const bf16x8* Bx = (const bf16x8*)(WiT + (size_t)(g * H_ + j0 + l16) * E_);
#pragma unroll
        for (int c = 0; c < 2; c++) {
            Wxreg[g][c] = Bx[wave * 8 + c * 4 + q];
            asm volatile("" : "+v"(Wxreg[g][c]));
        }
    }

    // ---- per-thread gate mapping / biases / fp32 state ----
    int Lp  = threadIdx.x & 63;
    int reg = threadIdx.x >> 6;
    int b_local = (Lp >> 4) * 4 + reg;
    int j_local = Lp & 15;
    int b = b0 + b_local, jg = j0 + j_local;
    float bhr = bh[jg];
    float bhz = bh[H_ + jg];
    float bhn = bh[2 * H_ + jg];
    asm volatile("" : "+v"(bhr), "+v"(bhz), "+v"(bhn));
    float hreg = 0.0f;

    const int tokrow = (b0 + l16) * L_;

    for (int t = 0; t < L_; t++) {
        const unsigned short* hist_t  = hist + (size_t)t * (B_ * H_);
        unsigned short*       hist_t1 = hist + (size_t)(t + 1) * (B_ * H_);

        // ---- xw partials (h-independent; before the poll) ----
        int tok = tokens[tokrow + t];
        const bf16x8* Ax = (const bf16x8*)(embB + (size_t)tok * E_);
        bf16x8 ax0 = Ax[wave * 8 + q];
        bf16x8 ax1 = Ax[wave * 8 + 4 + q];
        f32x4 xacc[3] = {};
#pragma unroll
        for (int g = 0; g < 3; g++) {
            xacc[g] = __builtin_amdgcn_mfma_f32_16x16x32_bf16(ax0, Wxreg[g][0], xacc[g], 0, 0, 0);
            xacc[g] = __builtin_amdgcn_mfma_f32_16x16x32_bf16(ax1, Wxreg[g][1], xacc[g], 0, 0, 0);
        }

        const unsigned short* p = hist_t + (size_t)(b0 + l16) * H_ + kbase + q * 8;
        bf16x8 a0, a1, a2, a3, a4, a5, a6, a7;

        // ---- poll group A (chunks 0-3, 128 B); passing iteration = the data ----
        {
            int spins = 0;
            while (true) {
                asm volatile("global_load_dwordx4 %0, %1, off sc0 sc1" : "=v"(a0) : "v"(p));
                asm volatile("global_load_dwordx4 %0, %1, off sc0 sc1" : "=v"(a1) : "v"(p + 32));
                asm volatile("global_load_dwordx4 %0, %1, off sc0 sc1" : "=v"(a2) : "v"(p + 64));
                asm volatile("global_load_dwordx4 %0, %1, off sc0 sc1" : "=v"(a3) : "v"(p + 96));
                asm volatile("s_waitcnt vmcnt(0)"
                             : "+v"(a0), "+v"(a1), "+v"(a2), "+v"(a3) :: "memory");
                int ok = chunk_ok(a0) & chunk_ok(a1) & chunk_ok(a2) & chunk_ok(a3);
                if (__all(ok)) break;
                if (++spins > (1 << 18)) break;   // fail loud, never hang
                __builtin_amdgcn_s_sleep(1);
            }
        }
        // ---- issue group B loads; overlap with group-A MFMAs ----
        asm volatile("global_load_dwordx4 %0, %1, off sc0 sc1" : "=v"(a4) : "v"(p + 128));
        asm volatile("global_load_dwordx4 %0, %1, off sc0 sc1" : "=v"(a5) : "v"(p + 160));
        asm volatile("global_load_dwordx4 %0, %1, off sc0 sc1" : "=v"(a6) : "v"(p + 192));
        asm volatile("global_load_dwordx4 %0, %1, off sc0 sc1" : "=v"(a7) : "v"(p + 224));

        f32x4 acc[3] = {};
#pragma unroll
        for (int g = 0; g < 3; g++) {
            acc[g] = __builtin_amdgcn_mfma_f32_16x16x32_bf16(a0, Wreg[g][0], acc[g], 0, 0, 0);
            acc[g] = __builtin_amdgcn_mfma_f32_16x16x32_bf16(a1, Wreg[g][1], acc[g], 0, 0, 0);
            acc[g] = __builtin_amdgcn_mfma_f32_16x16x32_bf16(a2, Wreg[g][2], acc[g], 0, 0, 0);
            acc[g] = __builtin_amdgcn_mfma_f32_16x16x32_bf16(a3, Wreg[g][3], acc[g], 0, 0, 0);
        }

        // ---- wait + check group B; retry only B on miss ----
        asm volatile("s_waitcnt vmcnt(0)"
                     : "+v"(a4), "+v"(a5), "+v"(a6), "+v"(a7) :: "memory");
        {
            int ok = chunk_ok(a4) & chunk_ok(a5) & chunk_ok(a6) & chunk_ok(a7);
            if (!__all(ok)) {
                int spins = 0;
                while (true) {
                    __builtin_amdgcn_s_sleep(1);
                    asm volatile("global_load_dwordx4 %0, %1, off sc0 sc1" : "=v"(a4) : "v"(p + 128));
                    asm volatile("global_load_dwordx4 %0, %1, off sc0 sc1" : "=v"(a5) : "v"(p + 160));
                    asm volatile("global_load_dwordx4 %0, %1, off sc0 sc1" : "=v"(a6) : "v"(p + 192));
                    asm volatile("global_load_dwordx4 %0, %1, off sc0 sc1" : "=v"(a7) : "v"(p + 224));
                    asm volatile("s_waitcnt vmcnt(0)"
                                 : "+v"(a4), "+v"(a5), "+v"(a6), "+v"(a7) :: "memory");
                    int ok2 = chunk_ok(a4) & chunk_ok(a5) & chunk_ok(a6) & chunk_ok(a7);
                    if (__all(ok2)) break;
                    if (++spins > (1 << 18)) break;
                }
            }
        }
#pragma unroll
        for (int g = 0; g < 3; g++) {
            acc[g] = __builtin_amdgcn_mfma_f32_16x16x32_bf16(a4, Wreg[g][4], acc[g], 0, 0, 0);
            acc[g] = __builtin_amdgcn_mfma_f32_16x16x32_bf16(a5, Wreg[g][5], acc[g], 0, 0, 0);
            acc[g] = __builtin_amdgcn_mfma_f32_16x16x32_bf16(a6, Wreg[g][6], acc[g], 0, 0, 0);
            acc[g] = __builtin_amdgcn_mfma_f32_16x16x32_bf16(a7, Wreg[g][7], acc[g], 0, 0, 0);
        }

        int par = t & 1;
#pragma unroll
        for (int g = 0; g < 3; g++) {
            red[par][wave][g][lane]     = acc[g];
            red[par][wave][3 + g][lane] = xacc[g];
        }
        __syncthreads();

        float gh0 = red[par][0][0][Lp][reg] + red[par][1][0][Lp][reg] + red[par][2][0][Lp][reg] + red[par][3][0][Lp][reg];
        float gh1 = red[par][0][1][Lp][reg] + red[par][1][1][Lp][reg] + red[par][2][1][Lp][reg] + red[par][3][1][Lp][reg];
        float gh2 = red[par][0][2][Lp][reg] + red[par][1][2][Lp][reg] + red[par][2][2][Lp][reg] + red[par][3][2][Lp][reg];
        float xr  = red[par][0][3][Lp][reg] + red[par][1][3][Lp][reg] + red[par][2][3][Lp][reg] + red[par][3][3][Lp][reg];
        float xz  = red[par][0][4][Lp][reg] + red[par][1][4][Lp][reg] + red[par][2][4][Lp][reg] + red[par][3][4][Lp][reg];
        float xn  = red[par][0][5][Lp][reg] + red[par][1][5][Lp][reg] + red[par][2][5][Lp][reg] + red[par][3][5][Lp][reg];

        float r = 1.0f / (1.0f + __expf(-(xr + gh0 + bhr)));
        float z = 1.0f / (1.0f + __expf(-(xz + gh1 + bhz)));
        float n = tanhf(xn + r * (gh2 + bhn));
        float hnew = (1.0f - z) * n + z * hreg;
        hreg = hnew;

        unsigned short hbv = f2bf(hnew);
        if (hbv == 0xAAAAu) hbv = 0xAAABu;   // never store the sentinel

        {
            unsigned short* hp = hist_t1 + (size_t)b * H_ + jg;
            unsigned hv32 = hbv;
            asm volatile("global_store_short %0, %1, off sc0 sc1"
                         :: "v"(hp), "v"(hv32) : "memory");
        }
        yB[((size_t)b * L_ + t) * H_ + jg] = hbv;   // cached; consumed after kernel end
    }
}

// ---- phase 3: logits[m][v] = y[m] @ Wout + bout   (M=16384, K=1024, N=256) ----
__global__ __launch_bounds__(256) void out_gemm(const unsigned short* __restrict__ yB,
                                                const unsigned short* __restrict__ WoutT,
                                                const float* __restrict__ bout,
                                                float* __restrict__ out) {
    int ntile = blockIdx.x;
    int mtile = blockIdx.y;
    int wave = threadIdx.x >> 6, lane = threadIdx.x & 63;
    int l16 = lane & 15, q = lane >> 4;

    int m = mtile * 64 + wave * 16 + l16;
    const bf16x8* Arow = (const bf16x8*)(yB + (size_t)m * H_);
    int n0 = ntile * 64;

    f32x4 acc[4] = {};
    for (int k0 = 0; k0 < H_; k0 += 32) {
        bf16x8 a = Arow[(k0 >> 3) + q];
#pragma unroll
        for (int j = 0; j < 4; j++) {
            const bf16x8* Brow = (const bf16x8*)(WoutT + (size_t)(n0 + j*16 + l16) * H_);
            bf16x8 b = Brow[(k0 >> 3) + q];
            acc[j] = __builtin_amdgcn_mfma_f32_16x16x32_bf16(a, b, acc[j], 0, 0, 0);
        }
    }
    int mrow = mtile * 64 + wave * 16 + q * 4;
#pragma unroll
    for (int j = 0; j < 4; j++) {
        int n = n0 + j * 16 + l16;
        float bias = bout[n];
#pragma unroll
        for (int r = 0; r < 4; r++)
            out[(size_t)(mrow + r) * V_ + n] = acc[j][r] + bias;
    }
}

extern "C" void kernel_launch(void* const* d_in, const int* in_sizes, int n_in,
                              void* d_out, int out_size, void* d_ws, size_t ws_size,
                              hipStream_t stream) {
    const int*   tokens = (const int*)  d_in[0];
    const float* emb    = (const float*)d_in[1];
    const float* Wi     = (const float*)d_in[2];
    const float* Wh     = (const float*)d_in[3];
    const float* bh     = (const float*)d_in[4];
    const float* Wout   = (const float*)d_in[5];
    const float* bout   = (const float*)d_in[6];
    float* out = (float*)d_out;

    char* ws = (char*)d_ws;
    size_t off = 0;
    auto alloc = [&](size_t bytes) -> void* {
        void* p = ws + off;
        off += (bytes + 255) & ~(size_t)255;
        return p;
    };
    unsigned short* WhT   = (unsigned short*)alloc((size_t)H3 * H_ * 2);   // 6 MB
    unsigned short* WiT   = (unsigned short*)alloc((size_t)H3 * E_ * 2);   // 1.5 MB
    unsigned short* WoutT = (unsigned short*)alloc((size_t)V_ * H_ * 2);   // 0.5 MB
    unsigned short* embB  = (unsigned short*)alloc((size_t)V_ * E_ * 2);   // 128 KB
    unsigned short* yB    = (unsigned short*)alloc((size_t)B_ * L_ * H_ * 2); // 32 MB
    unsigned short* hist  = (unsigned short*)alloc((size_t)(L_ + 1) * B_ * H_ * 2); // 33.7 MB

    prep_all<<<12544, 256, 0, stream>>>(Wh, Wi, Wout, emb, WhT, WiT, WoutT,
                                        embB, hist, (uint4*)(hist + (size_t)B_ * H_));

    {
        unsigned short* ah = hist;
        const unsigned short* aW = WhT; const unsigned short* aWx = WiT;
        const unsigned short* ae = embB; const int* at = tokens;
        const float* ab = bh; unsigned short* ay = yB;
        void* args[] = {&ah, &aW, &aWx, &ae, &at, &ab, &ay};
        hipError_t err = hipLaunchCooperativeKernel((void*)gru_persistent,
                                                    dim3(256), dim3(256), args, 0, stream);
        if (err != hipSuccess) {
            // fallback: plain launch; 256 blocks at 1 block/CU co-reside on 256 CUs,
            // and all spins are bounded (fail loud via absmax, not hang)
            gru_persistent<<<dim3(256), dim3(256), 0, stream>>>(
                ah, aW, aWx, ae, at, ab, ay);
        }
    }

    out_gemm<<<dim3(4, 256), 256, 0, stream>>>(yB, WoutT, bout, out);
}